// Round 1
// baseline (789.240 us; speedup 1.0000x reference)
//
#include <hip/hip_runtime.h>
#include <hip/hip_bf16.h>
#include <math.h>

// Problem constants (from reference)
#define T_TOK 8192            // B*S = 4*2048
#define HID   1024
#define NE    8
#define TOPKN 2
#define INTER 1408
#define NROWS (T_TOK*TOPKN)   // 16384 routed (token,expert) rows

typedef __attribute__((ext_vector_type(8))) __bf16 bf16x8;
typedef __attribute__((ext_vector_type(4))) float f32x4;
typedef __attribute__((ext_vector_type(4))) unsigned int u32x4;

__device__ __forceinline__ unsigned short f2bf(float f) {
    unsigned int u = __builtin_bit_cast(unsigned int, f);
    unsigned int lsb = (u >> 16) & 1u;
    u += 0x7fffu + lsb;            // round-to-nearest-even
    return (unsigned short)(u >> 16);
}

// ---------------------------------------------------------------- meta zero
__global__ void moe_zero_meta(int* counts, int* cursor) {
    int i = threadIdx.x;
    if (i < NE) { counts[i] = 0; cursor[i] = 0; }
}

// ---------------------------------------------------------------- router
// fp32 logits (exact vs ref), softmax, top-2; also casts x -> bf16.
__global__ __launch_bounds__(256) void moe_router(
    const float* __restrict__ x, const float* __restrict__ gate_w,
    unsigned short* __restrict__ xb, float* __restrict__ logits_out,
    int* __restrict__ topk_idx, float* __restrict__ topk_w,
    int* __restrict__ counts)
{
    __shared__ float gw[NE * HID];
    int tid = threadIdx.x;
    for (int i = tid; i < NE * HID / 4; i += 256)
        ((float4*)gw)[i] = ((const float4*)gate_w)[i];
    __syncthreads();

    int wave = tid >> 6, lane = tid & 63;
    int t = blockIdx.x * 4 + wave;
    const float* xrow = x + (size_t)t * HID;
    unsigned short* xbrow = xb + (size_t)t * HID;

    float acc[NE];
#pragma unroll
    for (int e = 0; e < NE; e++) acc[e] = 0.f;
#pragma unroll
    for (int j = 0; j < HID / 64; j++) {
        int h = j * 64 + lane;
        float xv = xrow[h];
        xbrow[h] = f2bf(xv);
#pragma unroll
        for (int e = 0; e < NE; e++) acc[e] += xv * gw[e * HID + h];
    }
#pragma unroll
    for (int e = 0; e < NE; e++) {
        float v = acc[e];
#pragma unroll
        for (int off = 32; off; off >>= 1) v += __shfl_xor(v, off, 64);
        acc[e] = v;
    }
    if (lane == 0) {
        float m = acc[0];
#pragma unroll
        for (int e = 1; e < NE; e++) m = fmaxf(m, acc[e]);
        float p[NE]; float s = 0.f;
#pragma unroll
        for (int e = 0; e < NE; e++) { p[e] = expf(acc[e] - m); s += p[e]; }
        float inv = 1.f / s;
#pragma unroll
        for (int e = 0; e < NE; e++) logits_out[(size_t)t * NE + e] = acc[e];
        // top-2 (strict > keeps lowest index on ties, matching lax.top_k)
        int i0 = 0;
#pragma unroll
        for (int e = 1; e < NE; e++) if (p[e] > p[i0]) i0 = e;
        int i1 = (i0 == 0) ? 1 : 0;
#pragma unroll
        for (int e = 0; e < NE; e++) if (e != i0 && p[e] > p[i1]) i1 = e;
        topk_idx[2 * t]     = i0; topk_w[2 * t]     = p[i0] * inv;
        topk_idx[2 * t + 1] = i1; topk_w[2 * t + 1] = p[i1] * inv;
        atomicAdd(&counts[i0], 1);
        atomicAdd(&counts[i1], 1);
    }
}

// ---------------------------------------------------------------- scan
__global__ void moe_scan(const int* __restrict__ counts, int* __restrict__ offsets) {
    if (threadIdx.x == 0) {
        int s = 0;
        for (int e = 0; e < NE; e++) { offsets[e] = s; s += counts[e]; }
        offsets[NE] = s;   // == NROWS
    }
}

// ---------------------------------------------------------------- scatter
__global__ __launch_bounds__(256) void moe_scatter(
    const int* __restrict__ topk_idx, const float* __restrict__ topk_w,
    const int* __restrict__ offsets, int* __restrict__ cursor,
    int* __restrict__ row_token, float* __restrict__ row_w,
    int* __restrict__ tok_rows)
{
    int t = blockIdx.x * 256 + threadIdx.x;
    if (t >= T_TOK) return;
#pragma unroll
    for (int k = 0; k < TOPKN; k++) {
        int e = topk_idx[2 * t + k];
        int pos = atomicAdd(&cursor[e], 1);
        int row = offsets[e] + pos;
        row_token[row] = t;
        row_w[row] = topk_w[2 * t + k];
        tok_rows[2 * t + k] = row;
    }
}

// ---------------------------------------------------------------- transpose+cast
// in: fp32 [NE][R_][C_]  ->  out: bf16 [NE][C_][R_]   (k-contiguous weights)
__global__ __launch_bounds__(256) void moe_transpose_cast(
    const float* __restrict__ in, unsigned short* __restrict__ out,
    int R_, int C_)
{
    __shared__ float tile[32][33];
    int e = blockIdx.z;
    const float* ine = in + (size_t)e * R_ * C_;
    unsigned short* oute = out + (size_t)e * R_ * C_;
    int c0 = blockIdx.x * 32, r0 = blockIdx.y * 32;
    int tx = threadIdx.x, ty = threadIdx.y;     // (32,8)
#pragma unroll
    for (int j = 0; j < 4; j++) {
        int r = r0 + ty + j * 8;
        tile[ty + j * 8][tx] = ine[(size_t)r * C_ + c0 + tx];
    }
    __syncthreads();
#pragma unroll
    for (int j = 0; j < 4; j++) {
        int c = c0 + ty + j * 8;
        oute[(size_t)c * R_ + r0 + tx] = f2bf(tile[tx][ty + j * 8]);
    }
}

// ---------------------------------------------------------------- grouped GEMM1
// h[row][i] = silu(x[tok] @ Wg) * (x[tok] @ Wu), per expert, bf16 MFMA 16x16x32.
#define BM 64
#define BN 64
#define BK 64
#define LDA 72   // +8 bf16 pad (16B) -> 2-way LDS conflict (free), 16B-aligned rows

__global__ __launch_bounds__(256) void moe_gemm1(
    const unsigned short* __restrict__ xb,
    const unsigned short* __restrict__ wg_t,   // [NE][INTER][HID]
    const unsigned short* __restrict__ wu_t,   // [NE][INTER][HID]
    const int* __restrict__ offsets, const int* __restrict__ row_token,
    unsigned short* __restrict__ h_buf)        // [NROWS][INTER]
{
    int e = blockIdx.z;
    int off = offsets[e], cnt = offsets[e + 1] - off;
    int row0 = blockIdx.y * BM;
    if (row0 >= cnt) return;
    int i0 = blockIdx.x * BN;

    __shared__ __align__(16) __bf16 As[BM][LDA];
    __shared__ __align__(16) __bf16 Bg[BN][LDA];
    __shared__ __align__(16) __bf16 Bu[BN][LDA];
    __shared__ int toks[BM];

    int tid = threadIdx.x;
    if (tid < BM) {
        int r = row0 + tid;
        toks[tid] = (r < cnt) ? row_token[off + r] : -1;
    }
    __syncthreads();

    const unsigned short* wg_e = wg_t + (size_t)e * INTER * HID + (size_t)i0 * HID;
    const unsigned short* wu_e = wu_t + (size_t)e * INTER * HID + (size_t)i0 * HID;

    f32x4 accg[4], accu[4];
#pragma unroll
    for (int n = 0; n < 4; n++) { accg[n] = {0.f,0.f,0.f,0.f}; accu[n] = {0.f,0.f,0.f,0.f}; }

    int wave = tid >> 6, lane = tid & 63;
    int l16 = lane & 15, quad = lane >> 4;

    for (int k0 = 0; k0 < HID; k0 += BK) {
        // stage A(64x64) + Bg + Bu: 512 16B-chunks each, 2 iters of 256 threads
#pragma unroll
        for (int it = 0; it < 2; it++) {
            int chunk = tid + it * 256;
            int m = chunk >> 3, c = chunk & 7;
            int tok = toks[m];
            u32x4 v = {0u,0u,0u,0u};
            if (tok >= 0) v = *(const u32x4*)(xb + (size_t)tok * HID + k0 + c * 8);
            *(u32x4*)(&As[m][c * 8]) = v;
            *(u32x4*)(&Bg[m][c * 8]) = *(const u32x4*)(wg_e + (size_t)m * HID + k0 + c * 8);
            *(u32x4*)(&Bu[m][c * 8]) = *(const u32x4*)(wu_e + (size_t)m * HID + k0 + c * 8);
        }
        __syncthreads();
#pragma unroll
        for (int kk = 0; kk < BK; kk += 32) {
            bf16x8 a = *(const bf16x8*)(&As[wave * 16 + l16][kk + quad * 8]);
#pragma unroll
            for (int n = 0; n < 4; n++) {
                bf16x8 bg = *(const bf16x8*)(&Bg[n * 16 + l16][kk + quad * 8]);
                bf16x8 bu = *(const bf16x8*)(&Bu[n * 16 + l16][kk + quad * 8]);
                accg[n] = __builtin_amdgcn_mfma_f32_16x16x32_bf16(a, bg, accg[n], 0, 0, 0);
                accu[n] = __builtin_amdgcn_mfma_f32_16x16x32_bf16(a, bu, accu[n], 0, 0, 0);
            }
        }
        __syncthreads();
    }
    // epilogue: silu(g)*u -> bf16  (C/D layout: col=lane&15, row=quad*4+reg)
#pragma unroll
    for (int n = 0; n < 4; n++) {
#pragma unroll
        for (int r = 0; r < 4; r++) {
            int m = wave * 16 + quad * 4 + r;
            int row = row0 + m;
            if (row < cnt) {
                float g = accg[n][r], u = accu[n][r];
                float hv = (g / (1.f + expf(-g))) * u;
                h_buf[(size_t)(off + row) * INTER + i0 + n * 16 + l16] = f2bf(hv);
            }
        }
    }
}

// ---------------------------------------------------------------- grouped GEMM2
// y[row][h] = w_row * (h[row] @ Wd), per expert.
__global__ __launch_bounds__(256) void moe_gemm2(
    const unsigned short* __restrict__ h_buf,  // [NROWS][INTER]
    const unsigned short* __restrict__ wd_t,   // [NE][HID][INTER]
    const int* __restrict__ offsets, const float* __restrict__ row_w,
    unsigned short* __restrict__ y_buf)        // [NROWS][HID]
{
    int e = blockIdx.z;
    int off = offsets[e], cnt = offsets[e + 1] - off;
    int row0 = blockIdx.y * BM;
    if (row0 >= cnt) return;
    int h0 = blockIdx.x * BN;

    __shared__ __align__(16) __bf16 As[BM][LDA];
    __shared__ __align__(16) __bf16 Bd[BN][LDA];

    int tid = threadIdx.x;
    const unsigned short* wd_e = wd_t + (size_t)e * HID * INTER + (size_t)h0 * INTER;

    f32x4 acc[4];
#pragma unroll
    for (int n = 0; n < 4; n++) acc[n] = {0.f,0.f,0.f,0.f};

    int wave = tid >> 6, lane = tid & 63;
    int l16 = lane & 15, quad = lane >> 4;

    for (int k0 = 0; k0 < INTER; k0 += BK) {
#pragma unroll
        for (int it = 0; it < 2; it++) {
            int chunk = tid + it * 256;
            int m = chunk >> 3, c = chunk & 7;
            int r = row0 + m;
            u32x4 v = {0u,0u,0u,0u};
            if (r < cnt) v = *(const u32x4*)(h_buf + (size_t)(off + r) * INTER + k0 + c * 8);
            *(u32x4*)(&As[m][c * 8]) = v;
            *(u32x4*)(&Bd[m][c * 8]) = *(const u32x4*)(wd_e + (size_t)m * INTER + k0 + c * 8);
        }
        __syncthreads();
#pragma unroll
        for (int kk = 0; kk < BK; kk += 32) {
            bf16x8 a = *(const bf16x8*)(&As[wave * 16 + l16][kk + quad * 8]);
#pragma unroll
            for (int n = 0; n < 4; n++) {
                bf16x8 b = *(const bf16x8*)(&Bd[n * 16 + l16][kk + quad * 8]);
                acc[n] = __builtin_amdgcn_mfma_f32_16x16x32_bf16(a, b, acc[n], 0, 0, 0);
            }
        }
        __syncthreads();
    }
#pragma unroll
    for (int n = 0; n < 4; n++) {
#pragma unroll
        for (int r = 0; r < 4; r++) {
            int m = wave * 16 + quad * 4 + r;
            int row = row0 + m;
            if (row < cnt) {
                float w = row_w[off + row];
                y_buf[(size_t)(off + row) * HID + h0 + n * 16 + l16] = f2bf(acc[n][r] * w);
            }
        }
    }
}

// ---------------------------------------------------------------- combine
// out[t][h] = y[row0_t][h] + y[row1_t][h]   (weights already applied)
__global__ __launch_bounds__(256) void moe_combine(
    const unsigned short* __restrict__ y_buf, const int* __restrict__ tok_rows,
    float* __restrict__ out)
{
    int gid = blockIdx.x * 256 + threadIdx.x;   // T*H/8 threads
    int t = gid >> 7;          // 128 chunks of 8 per token
    int c = gid & 127;
    u32x4 a = *(const u32x4*)(y_buf + (size_t)tok_rows[2 * t]     * HID + c * 8);
    u32x4 b = *(const u32x4*)(y_buf + (size_t)tok_rows[2 * t + 1] * HID + c * 8);
    float res[8];
#pragma unroll
    for (int j = 0; j < 4; j++) {
        unsigned int wa = a[j], wb = b[j];
        res[2 * j]     = __builtin_bit_cast(float, wa << 16)
                       + __builtin_bit_cast(float, wb << 16);
        res[2 * j + 1] = __builtin_bit_cast(float, wa & 0xffff0000u)
                       + __builtin_bit_cast(float, wb & 0xffff0000u);
    }
    float* o = out + (size_t)t * HID + c * 8;
    *(float4*)(o)     = make_float4(res[0], res[1], res[2], res[3]);
    *(float4*)(o + 4) = make_float4(res[4], res[5], res[6], res[7]);
}

// ---------------------------------------------------------------- launch
extern "C" void kernel_launch(void* const* d_in, const int* in_sizes, int n_in,
                              void* d_out, int out_size, void* d_ws, size_t ws_size,
                              hipStream_t stream)
{
    const float* x      = (const float*)d_in[0];   // [T,H]
    const float* gate_w = (const float*)d_in[1];   // [E,H]
    const float* w_gate = (const float*)d_in[2];   // [E,H,I]
    const float* w_up   = (const float*)d_in[3];   // [E,H,I]
    const float* w_down = (const float*)d_in[4];   // [E,I,H]
    float* out = (float*)d_out;                    // final [T,H] ++ logits [T,E]
    float* logits_out = out + (size_t)T_TOK * HID;

    char* ws = (char*)d_ws;
    // --- workspace layout (bytes) ---
    int*   counts    = (int*)(ws + 0);            // 8
    int*   cursor    = (int*)(ws + 32);           // 8
    int*   offsets   = (int*)(ws + 64);           // 9
    int*   topk_idx  = (int*)(ws + 256);                          // 65536
    float* topk_w    = (float*)(ws + 256 + 65536);                // 65536
    int*   row_token = (int*)(ws + 256 + 2 * 65536);              // 65536
    float* row_w     = (float*)(ws + 256 + 3 * 65536);            // 65536
    int*   tok_rows  = (int*)(ws + 256 + 4 * 65536);              // 65536
    size_t o = 256 + 5 * (size_t)65536 + 65280;   // -> 393216, 256-aligned w/ slack
    unsigned short* xb   = (unsigned short*)(ws + o); o += (size_t)T_TOK * HID * 2;   // 16.8 MB
    unsigned short* wg_t = (unsigned short*)(ws + o); o += (size_t)NE * INTER * HID * 2; // 23 MB
    unsigned short* wu_t = (unsigned short*)(ws + o); o += (size_t)NE * INTER * HID * 2; // 23 MB
    unsigned short* wd_t = (unsigned short*)(ws + o); o += (size_t)NE * HID * INTER * 2; // 23 MB
    unsigned short* h_buf = (unsigned short*)(ws + o); o += (size_t)NROWS * INTER * 2;   // 46 MB
    unsigned short* y_buf = (unsigned short*)(ws + o); o += (size_t)NROWS * HID * 2;     // 33.5 MB
    // total ~166.4 MB

    moe_zero_meta<<<1, 64, 0, stream>>>(counts, cursor);
    moe_router<<<T_TOK / 4, 256, 0, stream>>>(x, gate_w, xb, logits_out,
                                              topk_idx, topk_w, counts);
    moe_scan<<<1, 64, 0, stream>>>(counts, offsets);
    moe_scatter<<<T_TOK / 256, 256, 0, stream>>>(topk_idx, topk_w, offsets, cursor,
                                                 row_token, row_w, tok_rows);
    dim3 tb(32, 8, 1);
    moe_transpose_cast<<<dim3(INTER / 32, HID / 32, NE), tb, 0, stream>>>(w_gate, wg_t, HID, INTER);
    moe_transpose_cast<<<dim3(INTER / 32, HID / 32, NE), tb, 0, stream>>>(w_up,   wu_t, HID, INTER);
    moe_transpose_cast<<<dim3(HID / 32, INTER / 32, NE), tb, 0, stream>>>(w_down, wd_t, INTER, HID);

    moe_gemm1<<<dim3(INTER / BN, NROWS / BM, NE), 256, 0, stream>>>(
        xb, wg_t, wu_t, offsets, row_token, h_buf);
    moe_gemm2<<<dim3(HID / BN, NROWS / BM, NE), 256, 0, stream>>>(
        h_buf, wd_t, offsets, row_w, y_buf);
    moe_combine<<<(T_TOK * HID / 8) / 256, 256, 0, stream>>>(y_buf, tok_rows, out);
}